// Round 1
// baseline (231.688 us; speedup 1.0000x reference)
//
#include <hip/hip_runtime.h>

#define BATCH 4
#define NPTS 16384
#define NBOX 128          // M
#define NFEAT 128         // C
#define NS 512            // NUM_SAMPLED
#define ROW 131           // 3 + NFEAT
#define NWORDS (NPTS / 64)  // 256 mask words per box

__global__ __launch_bounds__(256) void roipool3d_kernel(
    const float* __restrict__ points,   // [B, N, 3]
    const float* __restrict__ feats,    // [B, N, C]
    const float* __restrict__ boxes,    // [B, M, 7]
    float* __restrict__ out_pooled,     // [B, M, NS, ROW]
    float* __restrict__ out_flag)       // [B, M]
{
#pragma clang fp contract(off)
    const int box_id = blockIdx.x;          // b*NBOX + m
    const int b      = box_id >> 7;         // / NBOX
    const int tid    = threadIdx.x;
    const int wave   = tid >> 6;
    const int lane   = tid & 63;

    __shared__ unsigned long long s_bits[NWORDS];  // 2 KB
    __shared__ int s_idx[NS];
    __shared__ int s_gi[NS];
    __shared__ int s_wsum[4];

    // Box parameters (broadcast reads)
    const float* bx = boxes + box_id * 7;
    const float cx = bx[0], cy = bx[1], cz = bx[2];
    // dims + 2*EXTRA_WIDTH, then *0.5 for half-extent
    const float hx = bx[3] * 0.5f + 1.0f;
    const float hy = bx[4] * 0.5f + 1.0f;
    const float hz = bx[5] * 0.5f + 1.0f;
    const double hd = (double)bx[6];
    const float ch = (float)cos(hd);
    const float sh = (float)sin(hd);

    const float* pts = points + (size_t)b * NPTS * 3;
    const float* fb  = feats  + (size_t)b * NPTS * NFEAT;

    // ---- Phase A: inside-mask bits, word w covers points [64w, 64w+64) ----
    for (int it = 0; it < NPTS / 256; ++it) {
        const int i = it * 256 + wave * 64 + lane;
        const float px = pts[i * 3 + 0];
        const float py = pts[i * 3 + 1];
        const float pz = pts[i * 3 + 2];
        const float sx = px - cx;
        const float sy = py - cy;
        const float sz = pz - cz;
        const float t0 = sx * ch;
        const float t1 = sy * sh;
        const float lx = t0 + t1;
        const float t2 = (-sx) * sh;
        const float t3 = sy * ch;
        const float ly = t2 + t3;
        const bool inside = (fabsf(lx) < hx) && (fabsf(ly) < hy) && (fabsf(sz) < hz);
        const unsigned long long m = __ballot(inside);
        if (lane == 0) s_bits[it * 4 + wave] = m;
    }
    __syncthreads();

    // ---- Phase B: ordered compaction of first NS inside indices ----
    // thread t owns mask word t (t in [0,256))
    const unsigned long long w = s_bits[tid];
    const int pc = __popcll(w);
    // inclusive wave scan of pc
    int pre = pc;
    #pragma unroll
    for (int off = 1; off < 64; off <<= 1) {
        const int v = __shfl_up(pre, off);
        if (lane >= off) pre += v;
    }
    if (lane == 63) s_wsum[wave] = pre;
    __syncthreads();
    int wbase = 0;
    for (int i = 0; i < wave; ++i) wbase += s_wsum[i];
    const int total = s_wsum[0] + s_wsum[1] + s_wsum[2] + s_wsum[3];
    int pos = wbase + (pre - pc);   // exclusive prefix for this word
    unsigned long long mm = w;
    while (mm && pos < NS) {
        const int bit = __builtin_ctzll(mm);
        s_idx[pos] = tid * 64 + bit;
        ++pos;
        mm &= (mm - 1);
    }
    const int cnt = (total < NS) ? total : NS;
    __syncthreads();

    // ---- Phase C: wrapped gather indices, then flat coalesced write ----
    float* outp = out_pooled + (size_t)box_id * NS * ROW;

    if (cnt == 0) {
        for (int idx = tid; idx < NS * ROW; idx += 256) outp[idx] = 0.0f;
        if (tid == 0) out_flag[box_id] = 1.0f;
        return;
    }

    for (int k = tid; k < NS; k += 256) {
        const int j = (k < cnt) ? k : (k % cnt);
        s_gi[k] = s_idx[j];
    }
    __syncthreads();

    for (int idx = tid; idx < NS * ROW; idx += 256) {
        const int k  = idx / ROW;
        const int c  = idx - k * ROW;
        const int gi = s_gi[k];
        const float v = (c < 3) ? pts[gi * 3 + c] : fb[gi * NFEAT + (c - 3)];
        outp[idx] = v;
    }
    if (tid == 0) out_flag[box_id] = 0.0f;
}

extern "C" void kernel_launch(void* const* d_in, const int* in_sizes, int n_in,
                              void* d_out, int out_size, void* d_ws, size_t ws_size,
                              hipStream_t stream) {
    const float* points = (const float*)d_in[0];   // [4,16384,3]
    const float* feats  = (const float*)d_in[1];   // [4,16384,128]
    const float* boxes  = (const float*)d_in[2];   // [4,128,7]
    float* out_pooled = (float*)d_out;
    float* out_flag   = out_pooled + (size_t)BATCH * NBOX * NS * ROW;

    roipool3d_kernel<<<BATCH * NBOX, 256, 0, stream>>>(
        points, feats, boxes, out_pooled, out_flag);
}

// Round 2
// 212.083 us; speedup vs baseline: 1.0924x; 1.0924x over previous
//
#include <hip/hip_runtime.h>

#define BATCH 4
#define NPTS 16384
#define NBOX 128          // M
#define NFEAT 128         // C
#define NS 512            // NUM_SAMPLED
#define ROW 131           // 3 + NFEAT
#define NWORDS (NPTS / 64)  // 256 mask words per box
#define ROWS_PER_BLK 32
#define SUBS (NS / ROWS_PER_BLK)   // 16 gather blocks per box

// ---------------- Kernel 1: mask + ordered compaction -> gather indices ----
__global__ __launch_bounds__(256) void mask_kernel(
    const float* __restrict__ points,   // [B, N, 3]
    const float* __restrict__ boxes,    // [B, M, 7]
    unsigned short* __restrict__ gi_ws, // [B*M, NS]
    int* __restrict__ cnt_ws,           // [B*M]
    float* __restrict__ out_flag)       // [B*M]
{
#pragma clang fp contract(off)
    const int box_id = blockIdx.x;          // b*NBOX + m
    const int b      = box_id >> 7;
    const int tid    = threadIdx.x;
    const int wave   = tid >> 6;
    const int lane   = tid & 63;

    __shared__ unsigned long long s_bits[NWORDS];  // 2 KB
    __shared__ int s_idx[NS];
    __shared__ int s_wsum[4];

    const float* bx = boxes + box_id * 7;
    const float cx = bx[0], cy = bx[1], cz = bx[2];
    const float hx = bx[3] * 0.5f + 1.0f;
    const float hy = bx[4] * 0.5f + 1.0f;
    const float hz = bx[5] * 0.5f + 1.0f;
    const double hd = (double)bx[6];
    const float ch = (float)cos(hd);
    const float sh = (float)sin(hd);

    const float* pts = points + (size_t)b * NPTS * 3;

    // Phase A: inside-mask bits, word w covers points [64w, 64w+64)
    for (int it = 0; it < NPTS / 256; ++it) {
        const int i = it * 256 + wave * 64 + lane;
        const float px = pts[i * 3 + 0];
        const float py = pts[i * 3 + 1];
        const float pz = pts[i * 3 + 2];
        const float sx = px - cx;
        const float sy = py - cy;
        const float sz = pz - cz;
        const float t0 = sx * ch;
        const float t1 = sy * sh;
        const float lx = t0 + t1;
        const float t2 = (-sx) * sh;
        const float t3 = sy * ch;
        const float ly = t2 + t3;
        const bool inside = (fabsf(lx) < hx) && (fabsf(ly) < hy) && (fabsf(sz) < hz);
        const unsigned long long m = __ballot(inside);
        if (lane == 0) s_bits[it * 4 + wave] = m;
    }
    __syncthreads();

    // Phase B: ordered compaction of first NS inside indices
    const unsigned long long w = s_bits[tid];
    const int pc = __popcll(w);
    int pre = pc;
    #pragma unroll
    for (int off = 1; off < 64; off <<= 1) {
        const int v = __shfl_up(pre, off);
        if (lane >= off) pre += v;
    }
    if (lane == 63) s_wsum[wave] = pre;
    __syncthreads();
    int wbase = 0;
    for (int i = 0; i < wave; ++i) wbase += s_wsum[i];
    const int total = s_wsum[0] + s_wsum[1] + s_wsum[2] + s_wsum[3];
    int pos = wbase + (pre - pc);
    unsigned long long mm = w;
    while (mm && pos < NS) {
        const int bit = __builtin_ctzll(mm);
        s_idx[pos] = tid * 64 + bit;
        ++pos;
        mm &= (mm - 1);
    }
    const int cnt = (total < NS) ? total : NS;
    __syncthreads();

    if (tid == 0) {
        cnt_ws[box_id] = cnt;
        out_flag[box_id] = (cnt == 0) ? 1.0f : 0.0f;
    }
    if (cnt > 0) {
        for (int k = tid; k < NS; k += 256) {
            const int j = (k < cnt) ? k : (k % cnt);
            gi_ws[box_id * NS + k] = (unsigned short)s_idx[j];
        }
    }
}

// ---------------- Kernel 2: vectorized gather + dense write ----------------
__global__ __launch_bounds__(256) void gather_kernel(
    const float* __restrict__ points,         // [B, N, 3]
    const float* __restrict__ feats,          // [B, N, C]
    const unsigned short* __restrict__ gi_ws, // [B*M, NS]
    const int* __restrict__ cnt_ws,           // [B*M]
    float* __restrict__ out_pooled)           // [B, M, NS, ROW]
{
    const int blk    = blockIdx.x;        // box_id * SUBS + sub
    const int box_id = blk >> 4;
    const int sub    = blk & (SUBS - 1);
    const int b      = box_id >> 7;
    const int tid    = threadIdx.x;
    const int wave   = tid >> 6;
    const int lane   = tid & 63;

    __shared__ float s_row[ROWS_PER_BLK * ROW];   // 16768 B
    __shared__ unsigned short s_gi[ROWS_PER_BLK];

    const int cnt = cnt_ws[box_id];
    // blk * 32*131 floats: region is 16B-aligned (16768 % 16 == 0)
    float* outg = out_pooled + (size_t)blk * (ROWS_PER_BLK * ROW);

    if (cnt == 0) {
        float4 z = make_float4(0.f, 0.f, 0.f, 0.f);
        float4* og = (float4*)outg;
        for (int i = tid; i < (ROWS_PER_BLK * ROW) / 4; i += 256) og[i] = z;
        return;
    }

    if (tid < ROWS_PER_BLK) s_gi[tid] = gi_ws[box_id * NS + sub * ROWS_PER_BLK + tid];
    __syncthreads();

    const float* pts = points + (size_t)b * NPTS * 3;
    const float* fb  = feats  + (size_t)b * NPTS * NFEAT;

    const int cg = lane & 31;   // feature float4-group 0..31
    const int rh = lane >> 5;   // which of the 2 rows this half-wave handles
    #pragma unroll
    for (int it = 0; it < 4; ++it) {
        const int row = wave * 8 + it * 2 + rh;
        const int gi  = s_gi[row];
        const float4 f = *(const float4*)(fb + (size_t)gi * NFEAT + cg * 4);
        float* sr = s_row + row * ROW;
        sr[3 + cg * 4 + 0] = f.x;
        sr[3 + cg * 4 + 1] = f.y;
        sr[3 + cg * 4 + 2] = f.z;
        sr[3 + cg * 4 + 3] = f.w;
        if (cg < 3) sr[cg] = pts[gi * 3 + cg];
    }
    __syncthreads();

    const float4* sv = (const float4*)s_row;
    float4* og = (float4*)outg;
    for (int i = tid; i < (ROWS_PER_BLK * ROW) / 4; i += 256) og[i] = sv[i];
}

extern "C" void kernel_launch(void* const* d_in, const int* in_sizes, int n_in,
                              void* d_out, int out_size, void* d_ws, size_t ws_size,
                              hipStream_t stream) {
    const float* points = (const float*)d_in[0];   // [4,16384,3]
    const float* feats  = (const float*)d_in[1];   // [4,16384,128]
    const float* boxes  = (const float*)d_in[2];   // [4,128,7]
    float* out_pooled = (float*)d_out;
    float* out_flag   = out_pooled + (size_t)BATCH * NBOX * NS * ROW;

    unsigned short* gi_ws = (unsigned short*)d_ws;            // 512*512*2 = 524288 B
    int* cnt_ws = (int*)(gi_ws + (size_t)BATCH * NBOX * NS);  // +2048 B

    mask_kernel<<<BATCH * NBOX, 256, 0, stream>>>(points, boxes, gi_ws, cnt_ws, out_flag);
    gather_kernel<<<BATCH * NBOX * SUBS, 256, 0, stream>>>(points, feats, gi_ws, cnt_ws, out_pooled);
}

// Round 3
// 190.672 us; speedup vs baseline: 1.2151x; 1.1123x over previous
//
#include <hip/hip_runtime.h>

#define BATCH 4
#define NPTS 16384
#define NBOX 128          // M
#define NFEAT 128         // C
#define NS 512            // NUM_SAMPLED
#define ROW 131           // 3 + NFEAT
#define NWORDS (NPTS / 64)   // 256 mask words per box
#define QCHUNK 4096          // points per ballot block
#define ROWS_PER_BLK 32
#define SUBS (NS / ROWS_PER_BLK)   // 16 gather blocks per box

// ---------- Kernel 1: ballot mask words, 4 blocks per box -----------------
__global__ __launch_bounds__(256) void ballot_kernel(
    const float* __restrict__ points,          // [B, N, 3]
    const float* __restrict__ boxes,           // [B, M, 7]
    unsigned long long* __restrict__ bits_ws)  // [B*M, NWORDS]
{
#pragma clang fp contract(off)
    const int blk    = blockIdx.x;       // box_id * 4 + q
    const int box_id = blk >> 2;
    const int q      = blk & 3;
    const int b      = box_id >> 7;
    const int tid    = threadIdx.x;
    const int wave   = tid >> 6;
    const int lane   = tid & 63;

    const float* bx = boxes + box_id * 7;
    const float cx = bx[0], cy = bx[1], cz = bx[2];
    const float hx = bx[3] * 0.5f + 1.0f;
    const float hy = bx[4] * 0.5f + 1.0f;
    const float hz = bx[5] * 0.5f + 1.0f;
    const double hd = (double)bx[6];
    const float ch = (float)cos(hd);
    const float sh = (float)sin(hd);

    const float* pts = points + (size_t)b * NPTS * 3;
    unsigned long long* bw = bits_ws + (size_t)box_id * NWORDS + q * (QCHUNK / 64);

    #pragma unroll 4
    for (int it = 0; it < QCHUNK / 256; ++it) {
        const int i = q * QCHUNK + it * 256 + wave * 64 + lane;
        const float px = pts[i * 3 + 0];
        const float py = pts[i * 3 + 1];
        const float pz = pts[i * 3 + 2];
        const float sx = px - cx;
        const float sy = py - cy;
        const float sz = pz - cz;
        const float t0 = sx * ch;
        const float t1 = sy * sh;
        const float lx = t0 + t1;
        const float t2 = (-sx) * sh;
        const float t3 = sy * ch;
        const float ly = t2 + t3;
        const bool inside = (fabsf(lx) < hx) && (fabsf(ly) < hy) && (fabsf(sz) < hz);
        const unsigned long long m = __ballot(inside);
        if (lane == 0) bw[it * 4 + wave] = m;
    }
}

// ---------- Kernel 2: redundant compaction + vectorized gather ------------
__global__ __launch_bounds__(256) void pool_kernel(
    const float* __restrict__ points,                // [B, N, 3]
    const float* __restrict__ feats,                 // [B, N, C]
    const unsigned long long* __restrict__ bits_ws,  // [B*M, NWORDS]
    float* __restrict__ out_pooled,                  // [B, M, NS, ROW]
    float* __restrict__ out_flag)                    // [B*M]
{
    const int blk    = blockIdx.x;        // box_id * SUBS + sub
    const int box_id = blk >> 4;
    const int sub    = blk & (SUBS - 1);
    const int b      = box_id >> 7;
    const int tid    = threadIdx.x;
    const int wave   = tid >> 6;
    const int lane   = tid & 63;

    __shared__ int s_idx[NS];                     // 2 KB
    __shared__ int s_gi[ROWS_PER_BLK];
    __shared__ int s_wsum[4];
    __shared__ float s_row[ROWS_PER_BLK * ROW];   // 16768 B

    // ---- compaction: thread t owns mask word t ----
    const unsigned long long w = bits_ws[(size_t)box_id * NWORDS + tid];
    const int pc = __popcll(w);
    int pre = pc;
    #pragma unroll
    for (int off = 1; off < 64; off <<= 1) {
        const int v = __shfl_up(pre, off);
        if (lane >= off) pre += v;
    }
    if (lane == 63) s_wsum[wave] = pre;
    __syncthreads();
    int wbase = 0;
    for (int i = 0; i < wave; ++i) wbase += s_wsum[i];
    const int total = s_wsum[0] + s_wsum[1] + s_wsum[2] + s_wsum[3];
    int pos = wbase + (pre - pc);
    unsigned long long mm = w;
    while (mm && pos < NS) {
        const int bit = __builtin_ctzll(mm);
        s_idx[pos] = tid * 64 + bit;
        ++pos;
        mm &= (mm - 1);
    }
    const int cnt = (total < NS) ? total : NS;
    __syncthreads();

    if (sub == 0 && tid == 0) out_flag[box_id] = (cnt == 0) ? 1.0f : 0.0f;

    float* outg = out_pooled + (size_t)blk * (ROWS_PER_BLK * ROW);

    if (cnt == 0) {
        float4 z = make_float4(0.f, 0.f, 0.f, 0.f);
        float4* og = (float4*)outg;
        for (int i = tid; i < (ROWS_PER_BLK * ROW) / 4; i += 256) og[i] = z;
        return;
    }

    if (tid < ROWS_PER_BLK) {
        const int k = sub * ROWS_PER_BLK + tid;
        const int j = (k < cnt) ? k : (k % cnt);
        s_gi[tid] = s_idx[j];
    }
    __syncthreads();

    const float* pts = points + (size_t)b * NPTS * 3;
    const float* fb  = feats  + (size_t)b * NPTS * NFEAT;

    const int cg = lane & 31;   // feature float4-group 0..31
    const int rh = lane >> 5;   // which of the 2 rows this half-wave handles
    #pragma unroll
    for (int it = 0; it < 4; ++it) {
        const int row = wave * 8 + it * 2 + rh;
        const int gi  = s_gi[row];
        const float4 f = *(const float4*)(fb + (size_t)gi * NFEAT + cg * 4);
        float* sr = s_row + row * ROW;
        sr[3 + cg * 4 + 0] = f.x;
        sr[3 + cg * 4 + 1] = f.y;
        sr[3 + cg * 4 + 2] = f.z;
        sr[3 + cg * 4 + 3] = f.w;
        if (cg < 3) sr[cg] = pts[gi * 3 + cg];
    }
    __syncthreads();

    const float4* sv = (const float4*)s_row;
    float4* og = (float4*)outg;
    for (int i = tid; i < (ROWS_PER_BLK * ROW) / 4; i += 256) og[i] = sv[i];
}

extern "C" void kernel_launch(void* const* d_in, const int* in_sizes, int n_in,
                              void* d_out, int out_size, void* d_ws, size_t ws_size,
                              hipStream_t stream) {
    const float* points = (const float*)d_in[0];   // [4,16384,3]
    const float* feats  = (const float*)d_in[1];   // [4,16384,128]
    const float* boxes  = (const float*)d_in[2];   // [4,128,7]
    float* out_pooled = (float*)d_out;
    float* out_flag   = out_pooled + (size_t)BATCH * NBOX * NS * ROW;

    unsigned long long* bits_ws = (unsigned long long*)d_ws;  // 512*256*8 = 1 MB

    ballot_kernel<<<BATCH * NBOX * 4, 256, 0, stream>>>(points, boxes, bits_ws);
    pool_kernel<<<BATCH * NBOX * SUBS, 256, 0, stream>>>(points, feats, bits_ws,
                                                         out_pooled, out_flag);
}